// Round 5
// baseline (133.531 us; speedup 1.0000x reference)
//
#include <hip/hip_runtime.h>

#define BB 4
#define CC 17
#define NN 4096
#define KN 7
#define NPTS (BB*NN)             // 16384
#define PAIRS (NPTS*KN)          // 114688
#define TT (CC*CC)               // 289
#define FINF 3.4e38f
#define SLC 8                    // candidate slices per batch
#define CSL (NN/SLC)             // 512
#define NTIL (CSL/16)            // 32 tiles per slice
#define TPAD 384                 // padded T row (bf16), 192 dwords
#define SM 6                     // per-lane survivor cap in merge

typedef float f32x4 __attribute__((ext_vector_type(4)));
typedef short short8 __attribute__((ext_vector_type(8)));

__device__ __forceinline__ unsigned int rne_bf16(float x) {
    unsigned int u = __float_as_uint(x);
    return (u + 0x7FFFu + ((u >> 16) & 1u)) >> 16;
}

// ---- Stage 1: transpose logits -> xs fp32[16384][24], xb bf16[16384][32], sq
__global__ __launch_bounds__(256) void prep_kernel(const float* __restrict__ logits,
                                                   float* __restrict__ xs,
                                                   unsigned short* __restrict__ xb,
                                                   float* __restrict__ sq) {
    int i = blockIdx.x * blockDim.x + threadIdx.x;
    if (i >= NPTS) return;
    int b = i >> 12;
    int n = i & (NN - 1);
    const float* base = logits + (size_t)b * CC * NN + n;
    float v[24];
    float s = 0.f;
#pragma unroll
    for (int c = 0; c < CC; ++c) { v[c] = base[(size_t)c * NN]; s = fmaf(v[c], v[c], s); }
#pragma unroll
    for (int c = CC; c < 24; ++c) v[c] = 0.f;
    float4* dst = (float4*)(xs + (size_t)i * 24);
#pragma unroll
    for (int q = 0; q < 6; ++q)
        dst[q] = make_float4(v[4*q], v[4*q+1], v[4*q+2], v[4*q+3]);
    sq[i] = s;
    unsigned int w[16];
#pragma unroll
    for (int t = 0; t < 16; ++t) {
        unsigned int u0 = (2*t   < CC) ? rne_bf16(v[2*t])   : 0u;
        unsigned int u1 = (2*t+1 < CC) ? rne_bf16(v[2*t+1]) : 0u;
        w[t] = u0 | (u1 << 16);
    }
    uint4* xd = (uint4*)(xb + (size_t)i * 32);
#pragma unroll
    for (int q = 0; q < 4; ++q)
        xd[q] = make_uint4(w[4*q], w[4*q+1], w[4*q+2], w[4*q+3]);
}

// ---- Stage 2a: per-(row,slice) upper bound on slice 8th-best rank ----------
__global__ __launch_bounds__(256) void passA_kernel(const unsigned short* __restrict__ xb,
                                                    const float* __restrict__ sq,
                                                    float* __restrict__ bounds) {
    int wid   = threadIdx.x >> 6;
    int lane  = threadIdx.x & 63;
    int strip = blockIdx.x * 4 + wid;      // 0..1023
    int s     = blockIdx.y;                // 0..SLC-1
    int b     = strip >> 8;
    int cb    = b * NN + s * CSL;
    int col   = lane & 15;
    int grp   = lane >> 4;
    int k0    = grp * 8;

    short8 A = *reinterpret_cast<const short8*>(xb + (size_t)(strip * 16 + col) * 32 + k0);
    const unsigned short* bp = xb + (size_t)(cb + col) * 32 + k0;
    const float* sp = sq + cb + col;

    f32x4 z = {0.f, 0.f, 0.f, 0.f};
    float mn[4] = {FINF, FINF, FINF, FINF};
#pragma unroll 8
    for (int t = 0; t < NTIL; ++t) {
        short8 Bf = *reinterpret_cast<const short8*>(bp + (size_t)t * 512);
        float sqv = sp[t * 16];
        f32x4 acc = __builtin_amdgcn_mfma_f32_16x16x32_bf16(A, Bf, z, 0, 0, 0);
#pragma unroll
        for (int j = 0; j < 4; ++j)
            mn[j] = fminf(mn[j], fmaf(-2.f, acc[j], sqv));
    }
    // 8 pop-min rounds over 16 lane-mins -> value >= slice true 8th-best (ties only loosen)
#pragma unroll
    for (int j = 0; j < 4; ++j) {
        float v = mn[j]; float m8 = FINF;
#pragma unroll
        for (int r = 0; r < 8; ++r) {
            float d = v;
            d = fminf(d, __shfl_xor(d, 1));
            d = fminf(d, __shfl_xor(d, 2));
            d = fminf(d, __shfl_xor(d, 4));
            d = fminf(d, __shfl_xor(d, 8));
            m8 = d;
            if (v == d) v = FINF;
        }
        if (col == 0)
            bounds[(strip * 16 + grp * 4 + j) * SLC + s] = m8;
    }
}

// ---- Stage 2b: thr_row = min over slices + margin (bf16-error cover) -------
__global__ __launch_bounds__(256) void thr_kernel(const float* __restrict__ bounds,
                                                  float* __restrict__ thr) {
    int i = blockIdx.x * blockDim.x + threadIdx.x;
    if (i >= NPTS) return;
    float m = FINF;
#pragma unroll
    for (int s = 0; s < SLC; ++s) m = fminf(m, bounds[i * SLC + s]);
    thr[i] = m + 0.5f + 0.005f * fabsf(m);
}

// ---- Stage 2c: bitmask of candidates with bf16-rank < thr ------------------
__global__ __launch_bounds__(256) void passB_kernel(const unsigned short* __restrict__ xb,
                                                    const float* __restrict__ sq,
                                                    const float* __restrict__ thr,
                                                    unsigned int* __restrict__ bitmask) {
    int wid   = threadIdx.x >> 6;
    int lane  = threadIdx.x & 63;
    int strip = blockIdx.x * 4 + wid;
    int s     = blockIdx.y;
    int b     = strip >> 8;
    int cb    = b * NN + s * CSL;
    int col   = lane & 15;
    int grp   = lane >> 4;
    int k0    = grp * 8;

    short8 A = *reinterpret_cast<const short8*>(xb + (size_t)(strip * 16 + col) * 32 + k0);
    const unsigned short* bp = xb + (size_t)(cb + col) * 32 + k0;
    const float* sp = sq + cb + col;

    float tj[4];
#pragma unroll
    for (int j = 0; j < 4; ++j) tj[j] = thr[strip * 16 + grp * 4 + j];

    f32x4 z = {0.f, 0.f, 0.f, 0.f};
    unsigned int m[4] = {0u, 0u, 0u, 0u};
#pragma unroll
    for (int t = 0; t < NTIL; ++t) {
        short8 Bf = *reinterpret_cast<const short8*>(bp + (size_t)t * 512);
        float sqv = sp[t * 16];
        f32x4 acc = __builtin_amdgcn_mfma_f32_16x16x32_bf16(A, Bf, z, 0, 0, 0);
#pragma unroll
        for (int j = 0; j < 4; ++j) {
            float r = fmaf(-2.f, acc[j], sqv);
            m[j] |= (r < tj[j]) ? (1u << t) : 0u;
        }
    }
#pragma unroll
    for (int j = 0; j < 4; ++j)
        bitmask[(size_t)(strip * 16 + grp * 4 + j) * 128 + s * 16 + col] = m[j];
}

__device__ __forceinline__ bool lexless(float ad, int ai, float bd, int bi) {
    return (ad < bd) || (ad == bd && ai < bi);
}

// ---- Stage 3: per-row fp32 recompute of survivors, exact top-8, emit 7 -----
__global__ __launch_bounds__(256) void merge_kernel(const unsigned int* __restrict__ bitmask,
                                                    const float* __restrict__ xs,
                                                    const float* __restrict__ sq,
                                                    int* __restrict__ nidx) {
    int wid  = threadIdx.x >> 6;
    int lane = threadIdx.x & 63;
    int row  = blockIdx.x * 4 + wid;
    int b    = row >> 12;
    int base = b * NN;

    const float4* qp = (const float4*)(xs + (size_t)row * 24);
    float q[20];
#pragma unroll
    for (int c = 0; c < 5; ++c) {
        float4 t = qp[c];
        q[4*c] = t.x; q[4*c+1] = t.y; q[4*c+2] = t.z; q[4*c+3] = t.w;
    }

    float smd[SM]; int smi[SM];
#pragma unroll
    for (int k = 0; k < SM; ++k) { smd[k] = FINF; smi[k] = 0x40000000 + lane * 8 + k; }

#pragma unroll
    for (int h = 0; h < 2; ++h) {
        int wi = lane + 64 * h;
        unsigned int w = bitmask[(size_t)row * 128 + wi];
        int s   = wi >> 4;
        int col = wi & 15;
        while (w) {
            int t = __ffs(w) - 1; w &= w - 1;
            int g = base + s * CSL + t * 16 + col;
            const float4* xp = (const float4*)(xs + (size_t)g * 24);
            float dot = 0.f;
#pragma unroll
            for (int c = 0; c < 5; ++c) {
                float4 xv = xp[c];
                dot = fmaf(q[4*c+0], xv.x, dot);
                dot = fmaf(q[4*c+1], xv.y, dot);
                dot = fmaf(q[4*c+2], xv.z, dot);
                dot = fmaf(q[4*c+3], xv.w, dot);
            }
            float r = fmaf(-2.f, dot, sq[g]);
            if (lexless(r, g, smd[SM-1], smi[SM-1])) {
                smd[SM-1] = r; smi[SM-1] = g;
#pragma unroll
                for (int k = SM - 1; k >= 1; --k) {
                    if (lexless(smd[k], smi[k], smd[k-1], smi[k-1])) {
                        float td = smd[k]; smd[k] = smd[k-1]; smd[k-1] = td;
                        int   ti = smi[k]; smi[k] = smi[k-1]; smi[k-1] = ti;
                    }
                }
            }
        }
    }

#pragma unroll
    for (int r = 0; r < 8; ++r) {
        float g = smd[0]; int gi = smi[0];
#pragma unroll
        for (int off = 32; off >= 1; off >>= 1) {
            float od = __shfl_xor(g, off);
            int   oi = __shfl_xor(gi, off);
            if (lexless(od, oi, g, gi)) { g = od; gi = oi; }
        }
        if (r >= 1 && lane == 0) nidx[(size_t)row * KN + (r - 1)] = gi;
        if (smi[0] == gi) {
#pragma unroll
            for (int k = 0; k < SM - 1; ++k) { smd[k] = smd[k+1]; smi[k] = smi[k+1]; }
            smd[SM-1] = FINF; smi[SM-1] = 0x50000000 + lane * 8 + r;
        }
    }
}

// ---- Stage 4a: insT fp32 -> bf16 rows padded to 384 ------------------------
__global__ __launch_bounds__(256) void prepT_kernel(const float* __restrict__ insT,
                                                    unsigned short* __restrict__ Tb) {
    int wid  = threadIdx.x >> 6;
    int lane = threadIdx.x & 63;
    int row  = blockIdx.x * 4 + wid;
    const float* src = insT + (size_t)row * TT;
    unsigned short* dst = Tb + (size_t)row * TPAD;
#pragma unroll
    for (int qd = 0; qd < 6; ++qd) {
        int e = lane + 64 * qd;
        float v = (e < TT) ? src[e] : 0.f;
        dst[e] = (unsigned short)rne_bf16(v);
    }
}

// ---- Stage 4b: wave-per-pair with bf16 T rows ------------------------------
__global__ __launch_bounds__(256) void pair_kernel(const float* __restrict__ xs,
                                                   const int* __restrict__ labels,
                                                   const unsigned int* __restrict__ Tb,
                                                   const int* __restrict__ nidx,
                                                   double* __restrict__ partials) {
    int wid  = threadIdx.x >> 6;
    int lane = threadIdx.x & 63;
    int wv   = blockIdx.x * 4 + wid;
    double acc = 0.0;
#pragma unroll 2
    for (int pp = 0; pp < 8; ++pp) {
        int p = wv * 8 + pp;
        int i = p / KN;
        int j = nidx[p];
        const unsigned int* Ti = Tb + (size_t)i * (TPAD / 2);
        const unsigned int* Tj = Tb + (size_t)j * (TPAD / 2);
        float td = 0.f;
#pragma unroll
        for (int qd = 0; qd < 3; ++qd) {
            unsigned int aw = Ti[lane + 64 * qd];
            unsigned int bw = Tj[lane + 64 * qd];
            float dlo = __uint_as_float(aw << 16)          - __uint_as_float(bw << 16);
            float dhi = __uint_as_float(aw & 0xFFFF0000u)  - __uint_as_float(bw & 0xFFFF0000u);
            td = fmaf(dlo, dlo, td);
            td = fmaf(dhi, dhi, td);
        }
        float dp = 0.f;
        if (lane < 20) {
            float df = xs[(size_t)i * 24 + lane] - xs[(size_t)j * 24 + lane];
            dp = df * df;
        }
#pragma unroll
        for (int off = 32; off >= 1; off >>= 1) {
            td += __shfl_xor(td, off);
            dp += __shfl_xor(dp, off);
        }
        if (lane == 0) {
            float eij = expf(-0.5f * dp);
            float sgn = (labels[j] == labels[i]) ? eij : -eij;
            acc += (double)sgn * (double)td;
        }
    }
    __shared__ double wsum[4];
    if (lane == 0) wsum[wid] = acc;
    __syncthreads();
    if (threadIdx.x == 0)
        partials[blockIdx.x] = wsum[0] + wsum[1] + wsum[2] + wsum[3];
}

// ---- Stage 4b': fp32 fallback (small workspace) ----------------------------
__global__ __launch_bounds__(256) void pair_f32_kernel(const float* __restrict__ xs,
                                                       const int* __restrict__ labels,
                                                       const float* __restrict__ insT,
                                                       const int* __restrict__ nidx,
                                                       double* __restrict__ partials) {
    int wid  = threadIdx.x >> 6;
    int lane = threadIdx.x & 63;
    int wv   = blockIdx.x * 4 + wid;
    double acc = 0.0;
#pragma unroll 1
    for (int pp = 0; pp < 8; ++pp) {
        int p = wv * 8 + pp;
        int i = p / KN;
        int j = nidx[p];
        const float* Ti = insT + (size_t)i * TT;
        const float* Tj = insT + (size_t)j * TT;
        float td = 0.f;
#pragma unroll
        for (int qd = 0; qd < 4; ++qd) {
            int e = lane + 64 * qd;
            float df = Ti[e] - Tj[e];
            td = fmaf(df, df, td);
        }
        if (lane < TT - 256) {
            float df = Ti[lane + 256] - Tj[lane + 256];
            td = fmaf(df, df, td);
        }
        float dp = 0.f;
        if (lane < 20) {
            float df = xs[(size_t)i * 24 + lane] - xs[(size_t)j * 24 + lane];
            dp = df * df;
        }
#pragma unroll
        for (int off = 32; off >= 1; off >>= 1) {
            td += __shfl_xor(td, off);
            dp += __shfl_xor(dp, off);
        }
        if (lane == 0) {
            float eij = expf(-0.5f * dp);
            float sgn = (labels[j] == labels[i]) ? eij : -eij;
            acc += (double)sgn * (double)td;
        }
    }
    __shared__ double wsum[4];
    if (lane == 0) wsum[wid] = acc;
    __syncthreads();
    if (threadIdx.x == 0)
        partials[blockIdx.x] = wsum[0] + wsum[1] + wsum[2] + wsum[3];
}

// ---- Stage 5: deterministic final reduce + mean ----------------------------
__global__ __launch_bounds__(1024) void finalize_kernel(const double* __restrict__ partials,
                                                        int nparts, float* __restrict__ out) {
    __shared__ double red[1024];
    int t = threadIdx.x;
    double s = 0.0;
    for (int q = t; q < nparts; q += 1024) s += partials[q];
    red[t] = s;
    __syncthreads();
    for (int sft = 512; sft > 0; sft >>= 1) {
        if (t < sft) red[t] += red[t + sft];
        __syncthreads();
    }
    if (t == 0) out[0] = (float)(red[0] / (double)PAIRS);
}

extern "C" void kernel_launch(void* const* d_in, const int* in_sizes, int n_in,
                              void* d_out, int out_size, void* d_ws, size_t ws_size,
                              hipStream_t stream) {
    const float* logits = (const float*)d_in[0];
    const int*   labels = (const int*)d_in[1];
    const float* insT   = (const float*)d_in[2];
    float* out = (float*)d_out;

    // workspace layout (bytes)
    const size_t o_part = 0;                         // 3584 doubles (28672)
    const size_t o_nidx = 32768;                     // 458752
    const size_t o_sq   = o_nidx + 458752;           // 65536
    const size_t o_xs   = o_sq + 65536;              // 1572864
    const size_t o_ov   = o_xs + 1572864;            // overlap region @ 2129920
    // topk-phase view of overlap region:
    const size_t o_xb   = o_ov;                      // 1048576
    const size_t o_bnd  = o_xb + 1048576;            // 524288
    const size_t o_thr  = o_bnd + 524288;            // 65536
    const size_t o_bit  = o_thr + 65536;             // 8388608
    // pair-phase view (after merge): Tb overlays xb/bounds/thr/bitmask
    const size_t o_Tb   = o_ov;                      // 16384*384*2 = 12582912
    const size_t need_full = o_Tb + 12582912;        // 14712832

    char* ws = (char*)d_ws;
    const int NPAIRBLK = PAIRS / (8 * 4);            // 3584
    double*         partials = (double*)(ws + o_part);
    int*            nidx     = (int*)(ws + o_nidx);
    float*          sq       = (float*)(ws + o_sq);
    float*          xs       = (float*)(ws + o_xs);
    unsigned short* xb       = (unsigned short*)(ws + o_xb);
    float*          bounds   = (float*)(ws + o_bnd);
    float*          thr      = (float*)(ws + o_thr);
    unsigned int*   bitmask  = (unsigned int*)(ws + o_bit);
    unsigned short* Tb       = (unsigned short*)(ws + o_Tb);

    bool useTb = (ws_size >= need_full);

    hipLaunchKernelGGL(prep_kernel, dim3(NPTS / 256), dim3(256), 0, stream,
                       logits, xs, xb, sq);
    hipLaunchKernelGGL(passA_kernel, dim3(256, SLC), dim3(256), 0, stream,
                       xb, sq, bounds);
    hipLaunchKernelGGL(thr_kernel, dim3(NPTS / 256), dim3(256), 0, stream,
                       bounds, thr);
    hipLaunchKernelGGL(passB_kernel, dim3(256, SLC), dim3(256), 0, stream,
                       xb, sq, thr, bitmask);
    hipLaunchKernelGGL(merge_kernel, dim3(NPTS / 4), dim3(256), 0, stream,
                       bitmask, xs, sq, nidx);
    if (useTb) {
        hipLaunchKernelGGL(prepT_kernel, dim3(NPTS / 4), dim3(256), 0, stream,
                           insT, Tb);
        hipLaunchKernelGGL(pair_kernel, dim3(NPAIRBLK), dim3(256), 0, stream,
                           xs, labels, (const unsigned int*)Tb, nidx, partials);
    } else {
        hipLaunchKernelGGL(pair_f32_kernel, dim3(NPAIRBLK), dim3(256), 0, stream,
                           xs, labels, insT, nidx, partials);
    }
    hipLaunchKernelGGL(finalize_kernel, dim3(1), dim3(1024), 0, stream,
                       partials, NPAIRBLK, out);
}

// Round 6
// 101.652 us; speedup vs baseline: 1.3136x; 1.3136x over previous
//
#include <hip/hip_runtime.h>

#define BB 4
#define CC 17
#define NN 4096
#define KN 7
#define NPTS (BB*NN)             // 16384
#define PAIRS (NPTS*KN)          // 114688
#define TT (CC*CC)               // 289
#define FINF 3.4e38f
#define WSL 4                    // wave-slices per block (4 waves)
#define CSL 1024                 // candidates per wave-slice
#define NTW (CSL/16)             // 64 tiles per wave
#define SCAP 128                 // per-row survivor cap (LDS)

typedef float f32x4 __attribute__((ext_vector_type(4)));
typedef short short8 __attribute__((ext_vector_type(8)));

__device__ __forceinline__ unsigned int rne_bf16(float x) {
    unsigned int u = __float_as_uint(x);
    return (u + 0x7FFFu + ((u >> 16) & 1u)) >> 16;
}

__device__ __forceinline__ bool lexless(float ad, int ai, float bd, int bi) {
    return (ad < bd) || (ad == bd && ai < bi);
}

// ---- Stage 1: transpose logits -> xs fp32[16384][24], xb bf16[16384][32], sq
__global__ __launch_bounds__(256) void prep_kernel(const float* __restrict__ logits,
                                                   float* __restrict__ xs,
                                                   unsigned short* __restrict__ xb,
                                                   float* __restrict__ sq) {
    int i = blockIdx.x * blockDim.x + threadIdx.x;
    if (i >= NPTS) return;
    int b = i >> 12;
    int n = i & (NN - 1);
    const float* base = logits + (size_t)b * CC * NN + n;
    float v[24];
    float s = 0.f;
#pragma unroll
    for (int c = 0; c < CC; ++c) { v[c] = base[(size_t)c * NN]; s = fmaf(v[c], v[c], s); }
#pragma unroll
    for (int c = CC; c < 24; ++c) v[c] = 0.f;
    float4* dst = (float4*)(xs + (size_t)i * 24);
#pragma unroll
    for (int q = 0; q < 6; ++q)
        dst[q] = make_float4(v[4*q], v[4*q+1], v[4*q+2], v[4*q+3]);
    sq[i] = s;
    unsigned int w[16];
#pragma unroll
    for (int t = 0; t < 16; ++t) {
        unsigned int u0 = (2*t   < CC) ? rne_bf16(v[2*t])   : 0u;
        unsigned int u1 = (2*t+1 < CC) ? rne_bf16(v[2*t+1]) : 0u;
        w[t] = u0 | (u1 << 16);
    }
    uint4* xd = (uint4*)(xb + (size_t)i * 32);
#pragma unroll
    for (int q = 0; q < 4; ++q)
        xd[q] = make_uint4(w[4*q], w[4*q+1], w[4*q+2], w[4*q+3]);
}

// ---- Stage 2: fused kNN. Block = 16-row strip; wave = 1024-cand slice. ----
// Pass1: MFMA sweep, per-lane top-2 -> slice bound (8th of 32) -> LDS.
// Pass2: thr = min slice bounds + margin; MFMA re-sweep -> survivor append.
// Pass3: fp32 exact re-rank of survivors, drop self, emit 7 neighbors.
__global__ __launch_bounds__(256) void knn_kernel(const unsigned short* __restrict__ xb,
                                                  const float* __restrict__ sq,
                                                  const float* __restrict__ xs,
                                                  int* __restrict__ nidx) {
    int wid   = threadIdx.x >> 6;
    int lane  = threadIdx.x & 63;
    int strip = blockIdx.x;              // 0..1023
    int b     = strip >> 8;
    int cb    = b * NN + wid * CSL;
    int col   = lane & 15;
    int grp   = lane >> 4;
    int k0    = grp * 8;

    __shared__ float thr_lds[WSL][16];
    __shared__ int   scnt[16];
    __shared__ int   slist[16][SCAP];
    if (threadIdx.x < 16) scnt[threadIdx.x] = 0;

    short8 A = *reinterpret_cast<const short8*>(xb + (size_t)(strip * 16 + col) * 32 + k0);
    const unsigned short* bp = xb + (size_t)(cb + col) * 32 + k0;
    const float* sp = sq + cb + col;
    f32x4 z = {0.f, 0.f, 0.f, 0.f};

    // ---- Pass 1: per-lane top-2 per row-stream ----
    float t1[4], t2[4];
#pragma unroll
    for (int j = 0; j < 4; ++j) { t1[j] = FINF; t2[j] = FINF; }
#pragma unroll 8
    for (int t = 0; t < NTW; ++t) {
        short8 Bf = *reinterpret_cast<const short8*>(bp + (size_t)t * 512);
        float sqv = sp[t * 16];
        f32x4 acc = __builtin_amdgcn_mfma_f32_16x16x32_bf16(A, Bf, z, 0, 0, 0);
#pragma unroll
        for (int j = 0; j < 4; ++j) {
            float r  = fmaf(-2.f, acc[j], sqv);
            float hi = fmaxf(t1[j], r);
            t1[j] = fminf(t1[j], r);
            t2[j] = fminf(t2[j], hi);
        }
    }
    // slice bound = 8th smallest of {t1,t2} x 16 lanes (>= slice 8th-best)
#pragma unroll
    for (int j = 0; j < 4; ++j) {
        float a = t1[j], b2 = t2[j], m8 = FINF;
#pragma unroll
        for (int r = 0; r < 8; ++r) {
            float d = a;
            d = fminf(d, __shfl_xor(d, 1));
            d = fminf(d, __shfl_xor(d, 2));
            d = fminf(d, __shfl_xor(d, 4));
            d = fminf(d, __shfl_xor(d, 8));
            m8 = d;
            if (a == d) { a = b2; b2 = FINF; }
        }
        if (col == 0) thr_lds[wid][grp * 4 + j] = m8;
    }
    __syncthreads();

    // ---- Pass 2: bitmask sweep + LDS survivor append ----
    float tj[4];
#pragma unroll
    for (int j = 0; j < 4; ++j) {
        int rr = grp * 4 + j;
        float m = fminf(fminf(thr_lds[0][rr], thr_lds[1][rr]),
                        fminf(thr_lds[2][rr], thr_lds[3][rr]));
        tj[j] = m + 0.5f + 0.005f * fabsf(m);   // bf16-error cover
    }
    unsigned long long msk[4] = {0ull, 0ull, 0ull, 0ull};
#pragma unroll 4
    for (int t = 0; t < NTW; ++t) {
        short8 Bf = *reinterpret_cast<const short8*>(bp + (size_t)t * 512);
        float sqv = sp[t * 16];
        f32x4 acc = __builtin_amdgcn_mfma_f32_16x16x32_bf16(A, Bf, z, 0, 0, 0);
#pragma unroll
        for (int j = 0; j < 4; ++j) {
            float r = fmaf(-2.f, acc[j], sqv);
            msk[j] |= (r < tj[j]) ? (1ull << t) : 0ull;
        }
    }
#pragma unroll
    for (int j = 0; j < 4; ++j) {
        unsigned long long w = msk[j];
        int rloc = grp * 4 + j;
        while (w) {
            int t = __builtin_ctzll(w); w &= w - 1;
            int slot = atomicAdd(&scnt[rloc], 1);
            if (slot < SCAP) slist[rloc][slot] = cb + t * 16 + col;
        }
    }
    __syncthreads();

    // ---- Pass 3: exact fp32 selection; wave wid handles rows wid*4..+3 ----
#pragma unroll 1
    for (int rr4 = 0; rr4 < 4; ++rr4) {
        int rloc = wid * 4 + rr4;
        int rowg = strip * 16 + rloc;
        int n = scnt[rloc]; n = (n > SCAP) ? SCAP : n;

        const float4* qp = (const float4*)(xs + (size_t)rowg * 24);  // wave-uniform
        float qv[20];
#pragma unroll
        for (int c = 0; c < 5; ++c) {
            float4 t = qp[c];
            qv[4*c] = t.x; qv[4*c+1] = t.y; qv[4*c+2] = t.z; qv[4*c+3] = t.w;
        }

        float d1 = FINF, d2 = FINF;
        int   i1 = 0x40000000 + lane, i2 = 0x44000000 + lane;
#pragma unroll
        for (int h = 0; h < 2; ++h) {
            int slot = lane + 64 * h;
            if (slot < n) {
                int g = slist[rloc][slot];
                const float4* xp = (const float4*)(xs + (size_t)g * 24);
                float dot = 0.f;
#pragma unroll
                for (int c = 0; c < 5; ++c) {
                    float4 xv = xp[c];
                    dot = fmaf(qv[4*c+0], xv.x, dot);
                    dot = fmaf(qv[4*c+1], xv.y, dot);
                    dot = fmaf(qv[4*c+2], xv.z, dot);
                    dot = fmaf(qv[4*c+3], xv.w, dot);
                }
                float r = fmaf(-2.f, dot, sq[g]);
                if (g == rowg) r = FINF;         // drop self by identity
                if (h == 0) { d1 = r; i1 = g; } else { d2 = r; i2 = g; }
            }
        }
        if (lexless(d2, i2, d1, i1)) {
            float td = d1; d1 = d2; d2 = td;
            int   ti = i1; i1 = i2; i2 = ti;
        }

#pragma unroll
        for (int r = 0; r < KN; ++r) {
            float g = d1; int gi = i1;
#pragma unroll
            for (int off = 32; off >= 1; off >>= 1) {
                float od = __shfl_xor(g, off);
                int   oi = __shfl_xor(gi, off);
                if (lexless(od, oi, g, gi)) { g = od; gi = oi; }
            }
            if (lane == 0) nidx[(size_t)rowg * KN + r] = gi;
            if (i1 == gi) {                       // unique owner (indices unique)
                d1 = d2; i1 = i2;
                d2 = FINF; i2 = 0x48000000 + lane * 8 + r;
            }
        }
    }
}

// ---- Stage 3: wave-per-row pair terms (Ti loaded once, 7 Tj streamed) ------
__global__ __launch_bounds__(256) void pair_kernel(const float* __restrict__ xs,
                                                   const int* __restrict__ labels,
                                                   const float* __restrict__ insT,
                                                   const int* __restrict__ nidx,
                                                   double* __restrict__ partials) {
    int wid  = threadIdx.x >> 6;
    int lane = threadIdx.x & 63;
    int row  = blockIdx.x * 4 + wid;       // 0..16383
    int li   = labels[row];

    const float* Ti = insT + (size_t)row * TT;
    float tiv[5];
#pragma unroll
    for (int q = 0; q < 5; ++q) {
        int e = lane + 64 * q;
        tiv[q] = (e < TT) ? Ti[e] : 0.f;
    }
    float xi = (lane < 20) ? xs[(size_t)row * 24 + lane] : 0.f;

    double acc = 0.0;
#pragma unroll 1
    for (int kk = 0; kk < KN; ++kk) {
        int j = nidx[(size_t)row * KN + kk];
        const float* Tj = insT + (size_t)j * TT;
        float td = 0.f;
#pragma unroll
        for (int q = 0; q < 5; ++q) {
            int e = lane + 64 * q;
            if (e < TT) {
                float df = tiv[q] - Tj[e];
                td = fmaf(df, df, td);
            }
        }
        float dp = 0.f;
        if (lane < 20) {
            float df = xi - xs[(size_t)j * 24 + lane];
            dp = df * df;
        }
#pragma unroll
        for (int off = 32; off >= 1; off >>= 1) {
            td += __shfl_xor(td, off);
            dp += __shfl_xor(dp, off);
        }
        if (lane == 0) {
            float eij = expf(-0.5f * dp);
            float sgn = (labels[j] == li) ? eij : -eij;
            acc += (double)sgn * (double)td;
        }
    }
    __shared__ double wsum[4];
    if (lane == 0) wsum[wid] = acc;
    __syncthreads();
    if (threadIdx.x == 0)
        partials[blockIdx.x] = wsum[0] + wsum[1] + wsum[2] + wsum[3];
}

// ---- Stage 4: deterministic final reduce + mean ----------------------------
__global__ __launch_bounds__(1024) void finalize_kernel(const double* __restrict__ partials,
                                                        int nparts, float* __restrict__ out) {
    __shared__ double red[1024];
    int t = threadIdx.x;
    double s = 0.0;
    for (int q = t; q < nparts; q += 1024) s += partials[q];
    red[t] = s;
    __syncthreads();
    for (int sft = 512; sft > 0; sft >>= 1) {
        if (t < sft) red[t] += red[t + sft];
        __syncthreads();
    }
    if (t == 0) out[0] = (float)(red[0] / (double)PAIRS);
}

extern "C" void kernel_launch(void* const* d_in, const int* in_sizes, int n_in,
                              void* d_out, int out_size, void* d_ws, size_t ws_size,
                              hipStream_t stream) {
    const float* logits = (const float*)d_in[0];
    const int*   labels = (const int*)d_in[1];
    const float* insT   = (const float*)d_in[2];
    float* out = (float*)d_out;

    // workspace: partials(32KB) | nidx(448KB) | sq(64KB) | xs(1.5MB) | xb(1MB)
    char* ws = (char*)d_ws;
    const size_t o_part = 0;
    const size_t o_nidx = 32768;
    const size_t o_sq   = o_nidx + 458752;
    const size_t o_xs   = o_sq + 65536;
    const size_t o_xb   = o_xs + 1572864;

    double*         partials = (double*)(ws + o_part);
    int*            nidx     = (int*)(ws + o_nidx);
    float*          sq       = (float*)(ws + o_sq);
    float*          xs       = (float*)(ws + o_xs);
    unsigned short* xb       = (unsigned short*)(ws + o_xb);

    hipLaunchKernelGGL(prep_kernel, dim3(NPTS / 256), dim3(256), 0, stream,
                       logits, xs, xb, sq);
    hipLaunchKernelGGL(knn_kernel, dim3(NPTS / 16), dim3(256), 0, stream,
                       xb, sq, xs, nidx);
    hipLaunchKernelGGL(pair_kernel, dim3(NPTS / 4), dim3(256), 0, stream,
                       xs, labels, insT, nidx, partials);
    hipLaunchKernelGGL(finalize_kernel, dim3(1), dim3(1024), 0, stream,
                       partials, NPTS / 4, out);
}